// Round 1
// baseline (462.538 us; speedup 1.0000x reference)
//
#include <hip/hip_runtime.h>
#include <math.h>

#define G 5000
#define IN 64
#define D 128
#define E 240000
#define EG (E + G)
#define SLOPE 0.2f
#define GD (G * D)

__device__ __forceinline__ float leaky(float v) { return v >= 0.f ? v : SLOPE * v; }

// ---------------- K0: zero the accumulator region ----------------
__global__ __launch_bounds__(256) void k_zero(float* __restrict__ p, int n) {
    int i = blockIdx.x * 256 + threadIdx.x;
    if (i < n) p[i] = 0.f;
}

// ---------------- K1: per-gene linear + relu ----------------
// h[g][d] = relu(sum_i x[g][i] * Win[g][i][d] + bin[g][d])
__global__ __launch_bounds__(128) void k_pergene(const float* __restrict__ x,
                                                 const float* __restrict__ Win,
                                                 const float* __restrict__ bin,
                                                 float* __restrict__ h) {
    int g = blockIdx.x;
    int d = threadIdx.x;
    __shared__ float xs[IN];
    if (d < IN) xs[d] = x[g * IN + d];
    __syncthreads();
    const float* W = Win + (size_t)g * IN * D + d;
    float acc = bin[g * D + d];
#pragma unroll
    for (int i = 0; i < IN; ++i) acc = fmaf(xs[i], W[(size_t)i * D], acc);
    h[g * D + d] = fmaxf(acc, 0.f);
}

// ---------------- K2: xl = h@Wl + bl ; xr = h@Wr + br ----------------
#define GPB 20
__global__ __launch_bounds__(128) void k_xlxr(const float* __restrict__ h,
                                              const float* __restrict__ Wl,
                                              const float* __restrict__ bl,
                                              const float* __restrict__ Wr,
                                              const float* __restrict__ br,
                                              float* __restrict__ xl,
                                              float* __restrict__ xr) {
    int g0 = blockIdx.x * GPB;
    int d = threadIdx.x;
    __shared__ float hs[GPB][D];
    for (int j = 0; j < GPB; ++j) hs[j][d] = h[(g0 + j) * D + d];
    __syncthreads();
    float al[GPB], ar[GPB];
    float blv = bl[d], brv = br[d];
#pragma unroll
    for (int j = 0; j < GPB; ++j) { al[j] = blv; ar[j] = brv; }
    for (int k = 0; k < D; ++k) {
        float wl = Wl[k * D + d];
        float wr = Wr[k * D + d];
#pragma unroll
        for (int j = 0; j < GPB; ++j) {
            al[j] = fmaf(hs[j][k], wl, al[j]);
            ar[j] = fmaf(hs[j][k], wr, ar[j]);
        }
    }
    for (int j = 0; j < GPB; ++j) {
        xl[(g0 + j) * D + d] = al[j];
        xr[(g0 + j) * D + d] = ar[j];
    }
}

// ---------------- K3: per-edge attention logit + denominator ----------------
// one 64-lane wave per edge; lanes hold 2 floats each
__global__ __launch_bounds__(256) void k_edge(const int* __restrict__ srcA,
                                              const int* __restrict__ dstA,
                                              const float* __restrict__ xl,
                                              const float* __restrict__ xr,
                                              const float* __restrict__ att,
                                              float* __restrict__ wbuf,
                                              float* __restrict__ zbuf) {
    int widx = (blockIdx.x * 256 + threadIdx.x) >> 6;
    int lane = threadIdx.x & 63;
    if (widx >= EG) return;
    int s, t;
    if (widx < E) { s = srcA[widx]; t = dstA[widx]; }
    else { s = widx - E; t = s; }
    float2 a  = *(const float2*)(att + lane * 2);
    float2 l2 = *(const float2*)(xl + s * D + lane * 2);
    float2 r2 = *(const float2*)(xr + t * D + lane * 2);
    float v = leaky(l2.x + r2.x) * a.x + leaky(l2.y + r2.y) * a.y;
#pragma unroll
    for (int off = 32; off; off >>= 1) v += __shfl_xor(v, off);
    if (lane == 0) {
        float wv = expf(v);
        wbuf[widx] = wv;
        atomicAdd(&zbuf[t], wv);
    }
}

// ---------------- K4: scatter weighted messages ----------------
__global__ __launch_bounds__(256) void k_scatter(const int* __restrict__ srcA,
                                                 const int* __restrict__ dstA,
                                                 const float* __restrict__ xl,
                                                 const float* __restrict__ wbuf,
                                                 const float* __restrict__ zbuf,
                                                 float* __restrict__ agg) {
    int widx = (blockIdx.x * 256 + threadIdx.x) >> 6;
    int lane = threadIdx.x & 63;
    if (widx >= EG) return;
    int s, t;
    if (widx < E) { s = srcA[widx]; t = dstA[widx]; }
    else { s = widx - E; t = s; }
    float alpha = wbuf[widx] / zbuf[t];
    float2 l2 = *(const float2*)(xl + s * D + lane * 2);
    atomicAdd(&agg[t * D + lane * 2], alpha * l2.x);
    atomicAdd(&agg[t * D + lane * 2 + 1], alpha * l2.y);
}

// ---------------- K5: MLP layer 1 (dominant: 328 MB of W1) ----------------
// h1acc[j] += sum_n leaky(agg[n] + bias[n&127]) * W1[n][j]
__global__ __launch_bounds__(256) void k_mlp1(const float* __restrict__ agg,
                                              const float* __restrict__ bias,
                                              const float* __restrict__ W1,
                                              float* __restrict__ h1acc) {
    const int NROWS = GD;
    int rows_per_block = (NROWS + gridDim.x - 1) / gridDim.x;
    int r0 = blockIdx.x * rows_per_block;
    int r1 = min(r0 + rows_per_block, NROWS);
    int j = threadIdx.x & 127;
    int half = threadIdx.x >> 7;
    float acc = 0.f;
    for (int n = r0 + half; n < r1; n += 2) {
        float f = leaky(agg[n] + bias[n & 127]);
        acc = fmaf(f, W1[(size_t)n * D + j], acc);
    }
    __shared__ float red[256];
    red[threadIdx.x] = acc;
    __syncthreads();
    if (half == 0) atomicAdd(&h1acc[j], acc + red[128 + j]);
}

// ---------------- K6: final relu + dot with W2 ----------------
__global__ __launch_bounds__(128) void k_final(const float* __restrict__ h1acc,
                                               const float* __restrict__ b1,
                                               const float* __restrict__ W2,
                                               const float* __restrict__ b2,
                                               float* __restrict__ out) {
    int j = threadIdx.x;
    float h1 = fmaxf(h1acc[j] + b1[j], 0.f);
    float v = h1 * W2[j];
#pragma unroll
    for (int off = 32; off; off >>= 1) v += __shfl_xor(v, off);
    __shared__ float s1;
    if (j == 64) s1 = v;
    __syncthreads();
    if (j == 0) out[0] = v + s1 + b2[0];
}

extern "C" void kernel_launch(void* const* d_in, const int* in_sizes, int n_in,
                              void* d_out, int out_size, void* d_ws, size_t ws_size,
                              hipStream_t stream) {
    const float* x    = (const float*)d_in[0];
    const int*   ei   = (const int*)d_in[1];
    const float* Win  = (const float*)d_in[2];
    const float* bin  = (const float*)d_in[3];
    const float* Wl   = (const float*)d_in[4];
    const float* bl   = (const float*)d_in[5];
    const float* Wr   = (const float*)d_in[6];
    const float* br   = (const float*)d_in[7];
    const float* att  = (const float*)d_in[8];
    const float* bias = (const float*)d_in[9];
    const float* W1   = (const float*)d_in[10];
    const float* b1   = (const float*)d_in[11];
    const float* W2   = (const float*)d_in[12];
    const float* b2   = (const float*)d_in[13];
    float* out = (float*)d_out;

    float* ws   = (float*)d_ws;
    float* h    = ws;            // G*D
    float* xl   = h + GD;        // G*D
    float* xr   = xl + GD;       // G*D
    float* wbuf = xr + GD;       // EG
    float* zbuf = wbuf + EG;     // G      -- zeroed region starts here
    float* agg  = zbuf + G;      // G*D
    float* h1a  = agg + GD;      // 128

    const int* srcA = ei;
    const int* dstA = ei + E;

    int nzero = G + GD + 128;
    k_zero<<<(nzero + 255) / 256, 256, 0, stream>>>(zbuf, nzero);
    k_pergene<<<G, 128, 0, stream>>>(x, Win, bin, h);
    k_xlxr<<<G / GPB, 128, 0, stream>>>(h, Wl, bl, Wr, br, xl, xr);
    k_edge<<<EG / 4, 256, 0, stream>>>(srcA, dstA, xl, xr, att, wbuf, zbuf);
    k_scatter<<<EG / 4, 256, 0, stream>>>(srcA, dstA, xl, wbuf, zbuf, agg);
    k_mlp1<<<2048, 256, 0, stream>>>(agg, bias, W1, h1a);
    k_final<<<1, 128, 0, stream>>>(h1a, b1, W2, b2, out);
}

// Round 2
// 249.540 us; speedup vs baseline: 1.8536x; 1.8536x over previous
//
#include <hip/hip_runtime.h>
#include <math.h>

#define G 5000
#define IN 64
#define D 128
#define E 240000
#define EG (E + G)
#define SLOPE 0.2f
#define GD (G * D)
#define MB 1024   // k_mlp1 blocks

__device__ __forceinline__ float leaky(float v) { return v >= 0.f ? v : SLOPE * v; }

// ---------------- zero int buffer ----------------
__global__ __launch_bounds__(256) void k_zero32(int* __restrict__ p, int n) {
    int i = blockIdx.x * 256 + threadIdx.x;
    if (i < n) p[i] = 0;
}

// ---------------- K1: per-gene linear + relu (one wave per gene) ----------------
__global__ __launch_bounds__(256) void k_pergene(const float* __restrict__ x,
                                                 const float* __restrict__ Win,
                                                 const float* __restrict__ bin,
                                                 float* __restrict__ h) {
    int g = (blockIdx.x * 256 + threadIdx.x) >> 6;
    int lane = threadIdx.x & 63;
    if (g >= G) return;
    float xv = x[g * IN + lane];                       // lane holds x[g][lane]
    const float* W = Win + (size_t)g * IN * D + lane * 2;
    float2 acc = *(const float2*)(bin + g * D + lane * 2);
#pragma unroll
    for (int i = 0; i < IN; ++i) {
        float xi = __shfl(xv, i);
        float2 w2 = *(const float2*)(W + (size_t)i * D);
        acc.x = fmaf(xi, w2.x, acc.x);
        acc.y = fmaf(xi, w2.y, acc.y);
    }
    float2 o = { fmaxf(acc.x, 0.f), fmaxf(acc.y, 0.f) };
    *(float2*)(h + g * D + lane * 2) = o;
}

// ---------------- K2: xl = h@Wl + bl ; xr = h@Wr + br ----------------
#define GPB 20
__global__ __launch_bounds__(128) void k_xlxr(const float* __restrict__ h,
                                              const float* __restrict__ Wl,
                                              const float* __restrict__ bl,
                                              const float* __restrict__ Wr,
                                              const float* __restrict__ br,
                                              float* __restrict__ xl,
                                              float* __restrict__ xr) {
    int g0 = blockIdx.x * GPB;
    int d = threadIdx.x;
    __shared__ float hs[GPB][D];
    for (int j = 0; j < GPB; ++j) hs[j][d] = h[(g0 + j) * D + d];
    __syncthreads();
    float al[GPB], ar[GPB];
    float blv = bl[d], brv = br[d];
#pragma unroll
    for (int j = 0; j < GPB; ++j) { al[j] = blv; ar[j] = brv; }
    for (int k = 0; k < D; ++k) {
        float wl = Wl[k * D + d];
        float wr = Wr[k * D + d];
#pragma unroll
        for (int j = 0; j < GPB; ++j) {
            al[j] = fmaf(hs[j][k], wl, al[j]);
            ar[j] = fmaf(hs[j][k], wr, ar[j]);
        }
    }
    for (int j = 0; j < GPB; ++j) {
        xl[(g0 + j) * D + d] = al[j];
        xr[(g0 + j) * D + d] = ar[j];
    }
}

// ---------------- K3a: histogram of destinations ----------------
__global__ __launch_bounds__(256) void k_hist(const int* __restrict__ dstA,
                                              int* __restrict__ cnt) {
    int i = blockIdx.x * 256 + threadIdx.x;
    if (i >= EG) return;
    int t = (i < E) ? dstA[i] : i - E;
    atomicAdd(&cnt[t], 1);
}

// ---------------- K3b: exclusive scan (single block) ----------------
__global__ __launch_bounds__(256) void k_scan(const int* __restrict__ cnt,
                                              int* __restrict__ rowptr,
                                              int* __restrict__ cursor) {
    __shared__ int ssum[256];
    int tid = threadIdx.x;
    const int CH = (G + 255) / 256;   // 20
    int base = tid * CH;
    int s = 0;
    for (int k = 0; k < CH; ++k) { int idx = base + k; if (idx < G) s += cnt[idx]; }
    ssum[tid] = s;
    __syncthreads();
    for (int off = 1; off < 256; off <<= 1) {
        int v = ssum[tid];
        int add = (tid >= off) ? ssum[tid - off] : 0;
        __syncthreads();
        ssum[tid] = v + add;
        __syncthreads();
    }
    int run = (tid == 0) ? 0 : ssum[tid - 1];
    for (int k = 0; k < CH; ++k) {
        int idx = base + k;
        if (idx < G) { rowptr[idx] = run; cursor[idx] = run; run += cnt[idx]; }
    }
    if (tid == 255) rowptr[G] = run;   // == EG
}

// ---------------- K3c: bucket edges by destination ----------------
__global__ __launch_bounds__(256) void k_bucket(const int* __restrict__ srcA,
                                                const int* __restrict__ dstA,
                                                int* __restrict__ cursor,
                                                int* __restrict__ ssrc) {
    int i = blockIdx.x * 256 + threadIdx.x;
    if (i >= EG) return;
    int s, t;
    if (i < E) { s = srcA[i]; t = dstA[i]; }
    else { s = i - E; t = s; }
    int pos = atomicAdd(&cursor[t], 1);
    ssrc[pos] = s;
}

// ---------------- K4: full GAT aggregation, one wave per destination ----------------
// f[t][:] = leaky( sum_e alpha_e * xl[src_e] + bias )
__global__ __launch_bounds__(256) void k_agg(const int* __restrict__ rowptr,
                                             const int* __restrict__ ssrc,
                                             const float* __restrict__ xl,
                                             const float* __restrict__ xr,
                                             const float* __restrict__ att,
                                             const float* __restrict__ bias,
                                             float* __restrict__ f) {
    int t = (blockIdx.x * 256 + threadIdx.x) >> 6;
    int lane = threadIdx.x & 63;
    if (t >= G) return;
    float2 a  = *(const float2*)(att + lane * 2);
    float2 r2 = *(const float2*)(xr + t * D + lane * 2);
    float2 acc = { 0.f, 0.f };
    float z = 0.f;
    int e0 = rowptr[t], e1 = rowptr[t + 1];
    for (int idx = e0; idx < e1; ++idx) {
        int s = ssrc[idx];
        float2 l2 = *(const float2*)(xl + s * D + lane * 2);
        float v = leaky(l2.x + r2.x) * a.x + leaky(l2.y + r2.y) * a.y;
#pragma unroll
        for (int off = 32; off; off >>= 1) v += __shfl_xor(v, off);
        float w = expf(v);
        z += w;
        acc.x = fmaf(w, l2.x, acc.x);
        acc.y = fmaf(w, l2.y, acc.y);
    }
    float2 b2 = *(const float2*)(bias + lane * 2);
    float inv = 1.f / z;
    float2 o = { leaky(fmaf(acc.x, inv, 0.f) + b2.x), leaky(acc.y * inv + b2.y) };
    *(float2*)(f + t * D + lane * 2) = o;
}

// ---------------- K5: MLP layer 1 -> per-block partials ----------------
__global__ __launch_bounds__(256) void k_mlp1(const float* __restrict__ f,
                                              const float* __restrict__ W1,
                                              float* __restrict__ partials) {
    const int rpb = GD / MB;              // 625 rows per block
    int r0 = blockIdx.x * rpb;
    int wave = threadIdx.x >> 6, lane = threadIdx.x & 63;
    float2 acc = { 0.f, 0.f };
#pragma unroll 4
    for (int n = r0 + wave; n < r0 + rpb; n += 4) {
        float fv = f[n];
        float2 w2 = *(const float2*)(W1 + (size_t)n * D + lane * 2);
        acc.x = fmaf(fv, w2.x, acc.x);
        acc.y = fmaf(fv, w2.y, acc.y);
    }
    __shared__ float2 red[4][64];
    red[wave][lane] = acc;
    __syncthreads();
    if (wave == 0) {
        float2 s = red[0][lane];
        s.x += red[1][lane].x + red[2][lane].x + red[3][lane].x;
        s.y += red[1][lane].y + red[2][lane].y + red[3][lane].y;
        *(float2*)(partials + blockIdx.x * D + lane * 2) = s;
    }
}

// ---------------- K6: reduce partials + relu + dot W2 ----------------
__global__ __launch_bounds__(1024) void k_final(const float* __restrict__ partials,
                                                const float* __restrict__ b1,
                                                const float* __restrict__ W2,
                                                const float* __restrict__ b2,
                                                float* __restrict__ out) {
    int tid = threadIdx.x;
    int j = tid & 127, seg = tid >> 7;    // 8 segments
    float s = 0.f;
    for (int b = seg; b < MB; b += 8) s += partials[b * D + j];
    __shared__ float red[1024];
    red[tid] = s;
    __syncthreads();
    if (seg == 0) {
        float tot = 0.f;
#pragma unroll
        for (int k = 0; k < 8; ++k) tot += red[k * 128 + j];
        float h1 = fmaxf(tot + b1[j], 0.f);
        red[j] = h1 * W2[j];
    }
    __syncthreads();
    if (tid == 0) {
        float o = b2[0];
        for (int k = 0; k < 128; ++k) o += red[k];
        out[0] = o;
    }
}

extern "C" void kernel_launch(void* const* d_in, const int* in_sizes, int n_in,
                              void* d_out, int out_size, void* d_ws, size_t ws_size,
                              hipStream_t stream) {
    const float* x    = (const float*)d_in[0];
    const int*   ei   = (const int*)d_in[1];
    const float* Win  = (const float*)d_in[2];
    const float* bin  = (const float*)d_in[3];
    const float* Wl   = (const float*)d_in[4];
    const float* bl   = (const float*)d_in[5];
    const float* Wr   = (const float*)d_in[6];
    const float* br   = (const float*)d_in[7];
    const float* att  = (const float*)d_in[8];
    const float* bias = (const float*)d_in[9];
    const float* W1   = (const float*)d_in[10];
    const float* b1   = (const float*)d_in[11];
    const float* W2   = (const float*)d_in[12];
    const float* b2   = (const float*)d_in[13];
    float* out = (float*)d_out;

    float* ws       = (float*)d_ws;
    float* h        = ws;                 // GD
    float* xl       = h  + GD;            // GD
    float* xr       = xl + GD;            // GD
    float* f        = xr + GD;            // GD
    float* partials = f  + GD;            // MB*D
    int*   ssrc     = (int*)(partials + (size_t)MB * D);  // EG
    int*   cnt      = ssrc + EG;          // G
    int*   rowptr   = cnt + G;            // G+1
    int*   cursor   = rowptr + G + 1;     // G

    const int* srcA = ei;
    const int* dstA = ei + E;

    k_zero32<<<(G + 255) / 256, 256, 0, stream>>>(cnt, G);
    k_pergene<<<(G * 64 + 255) / 256, 256, 0, stream>>>(x, Win, bin, h);
    k_xlxr<<<G / GPB, 128, 0, stream>>>(h, Wl, bl, Wr, br, xl, xr);
    k_hist<<<(EG + 255) / 256, 256, 0, stream>>>(dstA, cnt);
    k_scan<<<1, 256, 0, stream>>>(cnt, rowptr, cursor);
    k_bucket<<<(EG + 255) / 256, 256, 0, stream>>>(srcA, dstA, cursor, ssrc);
    k_agg<<<(G * 64 + 255) / 256, 256, 0, stream>>>(rowptr, ssrc, xl, xr, att, bias, f);
    k_mlp1<<<MB, 256, 0, stream>>>(f, W1, partials);
    k_final<<<1, 1024, 0, stream>>>(partials, b1, W2, b2, out);
}